// Round 7
// baseline (3516.602 us; speedup 1.0000x reference)
//
#include <hip/hip_runtime.h>

// Photonic layer: U = product of 2016 MZI 2x2 rotations (Reck mesh), then
// out = x @ U.T (complex), then tiny Kerr phase rotation.
//
// R7: R6 finally produced a clean absmax (6.86) instead of a crash ->
// (a) earlier aborts were d_out OOB writes; (b) INTERLEAVED complex layout
// is FALSIFIED (math verified analytically; interleaved would give ~1e-3).
// Surviving hypotheses, selected by out_size at launch:
//   out_size == 128*B -> PLANAR: flat = [all re (B*64) | all im (B*64)]
//   out_size ==  64*B -> real part only
// All d_out stores remain provably bounded by out_size.
//
// Math: LOSS_AMP = 10^(-0.05/20); Kerr phase = 2.6e-17*|o|^2 <= ~1e-15 rad,
// applied as exact-to-ulp first-order rotation (1, p).

#define PSIZE 64
#define N_PHASES 2016
#define NLAYER 63            // layers i=1..63, padded to 63 slots each
#define LOSS_AMP 0.99426007f
#define NL_COEFF 2.6e-17f

__global__ void fused_kernel(const float* __restrict__ phases,
                             const float* __restrict__ xr,
                             const float* __restrict__ xi,
                             float* __restrict__ out_re,  // re block base
                             float* __restrict__ out_im,  // im block base (or null)
                             int nrows) {                 // rows safe to write
  __shared__ __align__(16) float2 smem[PSIZE * PSIZE];  // 32 KB: cs then U
  const int tid = threadIdx.x;

  // --- Phase 1: per-step weights into smem[0..3968] (wave 0) ---
  if (tid < 64) {
    for (int idx = tid; idx < NLAYER * NLAYER; idx += 64) {
      const int li = idx / NLAYER;      // layer 0..62 (mesh layer i = li+1)
      const int m = idx - li * NLAYER;  // slot 0..62
      float2 w;
      if (m <= li) {                    // real MZI on modes (m, m+1)
        const int p = (li * (li + 1)) / 2 + m;
        const float th = phases[p];
        w = make_float2(LOSS_AMP * cosf(th), LOSS_AMP * sinf(th));
      } else {
        w = make_float2(1.0f, 0.0f);    // identity padding (no loss)
      }
      smem[idx] = w;
    }
  }
  __syncthreads();

  // --- Phase 2: wave 0 builds U columns in registers ---
  float ure[PSIZE], uim[PSIZE];
  if (tid < 64) {
#pragma unroll
    for (int r = 0; r < PSIZE; ++r) {
      ure[r] = (r == tid) ? 1.0f : 0.0f;
      uim[r] = 0.0f;
    }
    for (int li = 0; li < NLAYER; ++li) {
      const float2* w = &smem[li * NLAYER];
#pragma unroll
      for (int m = 0; m < NLAYER; ++m) {
        const float2 ww = w[m];         // wave-uniform LDS broadcast
        const float are = ure[m], aim = uim[m];
        const float bre = ure[m + 1], bim = uim[m + 1];
        // new_a = L*(c*a + i*s*b); new_b = L*(i*s*a + c*b)  (pre-scaled)
        ure[m]     = fmaf(ww.x, are, -ww.y * bim);
        uim[m]     = fmaf(ww.x, aim,  ww.y * bre);
        ure[m + 1] = fmaf(ww.x, bre, -ww.y * aim);
        uim[m + 1] = fmaf(ww.x, bim,  ww.y * are);
      }
    }
  }
  __syncthreads();  // all cs reads done before overwrite

  // --- Phase 3: U into smem, row-major: smem[r*64+c] = U[r][c] ---
  if (tid < 64) {
#pragma unroll
    for (int r = 0; r < PSIZE; ++r) {
      smem[r * PSIZE + tid] = make_float2(ure[r], uim[r]);
    }
  }
  __syncthreads();

  // --- Phase 4: one batch row per thread ---
  const int row = blockIdx.x * 256 + tid;
  if (row >= nrows) return;  // no barriers after this point

  float xre[PSIZE], xim[PSIZE];
  {
    // row*PSIZE*4 bytes is a multiple of 256 -> float4-aligned.
    const float4* xr4 = (const float4*)(xr + (size_t)row * PSIZE);
    const float4* xi4 = (const float4*)(xi + (size_t)row * PSIZE);
#pragma unroll
    for (int i = 0; i < 16; ++i) {
      float4 a = xr4[i];
      xre[4 * i] = a.x; xre[4 * i + 1] = a.y;
      xre[4 * i + 2] = a.z; xre[4 * i + 3] = a.w;
      float4 b = xi4[i];
      xim[4 * i] = b.x; xim[4 * i + 1] = b.y;
      xim[4 * i + 2] = b.z; xim[4 * i + 3] = b.w;
    }
  }

  float* orp = out_re + (size_t)row * PSIZE;   // 64 floats: re of this row
  float* oip = (out_im != nullptr) ? (out_im + (size_t)row * PSIZE) : nullptr;

  for (int j = 0; j < PSIZE; j += 2) {
    const float4* r0 = (const float4*)(smem + j * PSIZE);
    const float4* r1 = (const float4*)(smem + (j + 1) * PSIZE);
    float ar0 = 0.f, ai0 = 0.f, ar1 = 0.f, ai1 = 0.f;
#pragma unroll
    for (int k = 0; k < 32; ++k) {
      float4 u0 = r0[k];  // U[j][2k].(re,im), U[j][2k+1].(re,im)
      float4 u1 = r1[k];
      float a0 = xre[2 * k], b0 = xim[2 * k];
      float a1 = xre[2 * k + 1], b1 = xim[2 * k + 1];
      ar0 = fmaf(a0, u0.x, fmaf(-b0, u0.y, fmaf(a1, u0.z, fmaf(-b1, u0.w, ar0))));
      ai0 = fmaf(a0, u0.y, fmaf( b0, u0.x, fmaf(a1, u0.w, fmaf( b1, u0.z, ai0))));
      ar1 = fmaf(a0, u1.x, fmaf(-b0, u1.y, fmaf(a1, u1.z, fmaf(-b1, u1.w, ar1))));
      ai1 = fmaf(a0, u1.y, fmaf( b0, u1.x, fmaf(a1, u1.w, fmaf( b1, u1.z, ai1))));
    }
    // Kerr first-order rotation (exact at p <= ~1e-15).
    float p0 = NL_COEFF * fmaf(ar0, ar0, ai0 * ai0);
    float p1 = NL_COEFF * fmaf(ar1, ar1, ai1 * ai1);
    orp[j]     = fmaf(-ai0, p0, ar0);
    orp[j + 1] = fmaf(-ai1, p1, ar1);
    if (oip != nullptr) {
      oip[j]     = fmaf(ar0, p0, ai0);
      oip[j + 1] = fmaf(ar1, p1, ai1);
    }
  }
}

extern "C" void kernel_launch(void* const* d_in, const int* in_sizes, int n_in,
                              void* d_out, int out_size, void* d_ws, size_t ws_size,
                              hipStream_t stream) {
  // Identify inputs by size, not position: phases has exactly 2016 elements.
  int pidx = -1;
  for (int i = 0; i < n_in; ++i) {
    if (in_sizes[i] == N_PHASES) { pidx = i; break; }
  }
  if (pidx < 0) pidx = 2;  // fall back to dict order
  int xa = -1, xb = -1;
  for (int i = 0; i < n_in; ++i) {
    if (i == pidx) continue;
    if (xa < 0) xa = i;
    else if (xb < 0) xb = i;
  }
  if (xa < 0 || xb < 0) return;

  const float* phases = (const float*)d_in[pidx];
  const float* x_real = (const float*)d_in[xa];
  const float* x_imag = (const float*)d_in[xb];

  long b_in = (long)in_sizes[xa] / PSIZE;
  if ((long)in_sizes[xb] / PSIZE < b_in) b_in = (long)in_sizes[xb] / PSIZE;

  float* out = (float*)d_out;
  float* out_re = out;
  float* out_im = nullptr;
  long nrows;

  if ((long)out_size >= 2 * b_in * PSIZE) {
    // PLANAR: [all re (B*64) | all im (B*64)]; im block at out_size/2.
    const long half = (long)out_size / 2;
    out_im = out + half;
    long cap = half / PSIZE;               // rows each block can hold
    nrows = (b_in < cap) ? b_in : cap;
  } else {
    // Real-part-only buffer.
    long cap = (long)out_size / PSIZE;
    nrows = (b_in < cap) ? b_in : cap;
  }
  if (nrows <= 0) return;

  const int nblocks = (int)((nrows + 255) / 256);
  fused_kernel<<<nblocks, 256, 0, stream>>>(phases, x_real, x_imag,
                                            out_re, out_im, (int)nrows);
}